// Round 1
// baseline (459.379 us; speedup 1.0000x reference)
//
#include <hip/hip_runtime.h>
#include <math.h>

#define NH   16
#define SQL  4096
#define SKL  4096
#define DK   64
#define QB   128
#define KB   128
#define PADW 132   // padded LDS row stride (floats), multiple of 4 for float4 alignment

// Kernel 1: per-(head, q-block) streaming score statistics.
// Writes 3 floats per block to d_ws: [sum of scores, sum of row-maxes, sum of row-vars]
__global__ __launch_bounds__(256) void dtp_stats_kernel(const float* __restrict__ Q,
                                                        const float* __restrict__ K,
                                                        float* __restrict__ partial) {
    const int qb  = blockIdx.x;   // 0..31
    const int h   = blockIdx.y;   // 0..15
    const int tid = threadIdx.x;  // 0..255

    __shared__ float QT[DK][PADW];  // QT[d][r] : transposed Q tile
    __shared__ float KT[DK][PADW];  // KT[d][c] : transposed K tile
    __shared__ float bred[16][4];   // per-tr-group block partials

    const size_t hoff = (size_t)h * SQL * DK;
    const float* Qh = Q + hoff + (size_t)qb * QB * DK;
    const float* Kh = K + hoff;

    // ---- stage Q tile (transpose 128x64 -> QT[d][r]) ----
    #pragma unroll
    for (int j = 0; j < 8; ++j) {
        int idx = tid + 256 * j;        // 0..2047
        int r   = idx >> 4;             // 0..127
        int c4  = idx & 15;             // float4 chunk along d
        const float4 v = *reinterpret_cast<const float4*>(Qh + r * DK + 4 * c4);
        QT[4*c4+0][r] = v.x;
        QT[4*c4+1][r] = v.y;
        QT[4*c4+2][r] = v.z;
        QT[4*c4+3][r] = v.w;
    }

    const int tr = tid >> 4;    // 0..15 -> row group
    const int tc = tid & 15;    // 0..15 -> col group
    const int r0 = tr * 8;
    const int c0 = tc * 8;

    // per-thread running row stats for its 8 rows
    float rsum[8], rmax[8], rs1[8], rs2[8];
    #pragma unroll
    for (int i = 0; i < 8; ++i) { rsum[i] = 0.f; rmax[i] = -3.0e38f; rs1[i] = 0.f; rs2[i] = 0.f; }

    for (int kt = 0; kt < SKL / KB; ++kt) {
        __syncthreads();  // protect KT (and QT on first iter) before restaging
        // ---- stage K tile (transpose 128x64 -> KT[d][c]) ----
        #pragma unroll
        for (int j = 0; j < 8; ++j) {
            int idx = tid + 256 * j;
            int c   = idx >> 4;
            int c4  = idx & 15;
            const float4 v = *reinterpret_cast<const float4*>(Kh + (size_t)(kt * KB + c) * DK + 4 * c4);
            KT[4*c4+0][c] = v.x;
            KT[4*c4+1][c] = v.y;
            KT[4*c4+2][c] = v.z;
            KT[4*c4+3][c] = v.w;
        }
        __syncthreads();

        // ---- 8x8 register tile GEMM over d ----
        float acc[8][8];
        #pragma unroll
        for (int i = 0; i < 8; ++i)
            #pragma unroll
            for (int jj = 0; jj < 8; ++jj) acc[i][jj] = 0.f;

        #pragma unroll 4
        for (int d = 0; d < DK; ++d) {
            float qv[8], kv[8];
            const float4 t0 = *reinterpret_cast<const float4*>(&QT[d][r0]);
            const float4 t1 = *reinterpret_cast<const float4*>(&QT[d][r0 + 4]);
            const float4 u0 = *reinterpret_cast<const float4*>(&KT[d][c0]);
            const float4 u1 = *reinterpret_cast<const float4*>(&KT[d][c0 + 4]);
            qv[0]=t0.x; qv[1]=t0.y; qv[2]=t0.z; qv[3]=t0.w;
            qv[4]=t1.x; qv[5]=t1.y; qv[6]=t1.z; qv[7]=t1.w;
            kv[0]=u0.x; kv[1]=u0.y; kv[2]=u0.z; kv[3]=u0.w;
            kv[4]=u1.x; kv[5]=u1.y; kv[6]=u1.z; kv[7]=u1.w;
            #pragma unroll
            for (int i = 0; i < 8; ++i)
                #pragma unroll
                for (int jj = 0; jj < 8; ++jj)
                    acc[i][jj] = fmaf(qv[i], kv[jj], acc[i][jj]);
        }

        // ---- fold scores into row stats ----
        #pragma unroll
        for (int i = 0; i < 8; ++i) {
            #pragma unroll
            for (int jj = 0; jj < 8; ++jj) {
                float s = acc[i][jj] * 0.125f;          // / sqrt(64)
                s = fminf(fmaxf(s, -50.f), 50.f);        // clip (ref order: before everything)
                rsum[i] += s;
                rmax[i]  = fmaxf(rmax[i], s);
                float e = __expf(0.5f * s);              // exp(s/2); no overflow since |s|<=50
                rs1[i] += e;
                rs2[i]  = fmaf(e, e, rs2[i]);            // exp(s)
            }
        }
    }

    // ---- reduce row stats across the 16 tc-threads (16-lane contiguous groups) ----
    #pragma unroll
    for (int m = 1; m < 16; m <<= 1) {
        #pragma unroll
        for (int i = 0; i < 8; ++i) {
            rsum[i] += __shfl_xor(rsum[i], m, 64);
            rmax[i]  = fmaxf(rmax[i], __shfl_xor(rmax[i], m, 64));
            rs1[i]  += __shfl_xor(rs1[i], m, 64);
            rs2[i]  += __shfl_xor(rs2[i], m, 64);
        }
    }

    if (tc == 0) {
        float bs = 0.f, bm = 0.f, bv = 0.f;
        #pragma unroll
        for (int i = 0; i < 8; ++i) {
            bs += rsum[i];
            bm += rmax[i];
            float sumP2 = rs2[i] / (rs1[i] * rs1[i]);    // Σ p^2  (shift-invariant)
            float var = (sumP2 - (1.0f / (float)SKL)) / (float)(SKL - 1);
            bv += var;
        }
        bred[tr][0] = bs; bred[tr][1] = bm; bred[tr][2] = bv;
    }
    __syncthreads();
    if (tid == 0) {
        float bs = 0.f, bm = 0.f, bv = 0.f;
        #pragma unroll
        for (int i = 0; i < 16; ++i) { bs += bred[i][0]; bm += bred[i][1]; bv += bred[i][2]; }
        float* p = partial + (size_t)(blockIdx.y * 32 + blockIdx.x) * 3;
        p[0] = bs; p[1] = bm; p[2] = bv;
    }
}

// Kernel 2: reduce block partials per head, apply 3->16->1 MLP, write t.
__global__ __launch_bounds__(64) void dtp_finalize_kernel(const float* __restrict__ partial,
                                                          const float* __restrict__ W1,
                                                          const float* __restrict__ b1,
                                                          const float* __restrict__ W2,
                                                          const float* __restrict__ b2,
                                                          float* __restrict__ out) {
    int h = threadIdx.x;
    if (h >= NH) return;
    float ssum = 0.f, smax = 0.f, svar = 0.f;
    for (int qb = 0; qb < 32; ++qb) {
        const float* p = partial + (size_t)(h * 32 + qb) * 3;
        ssum += p[0]; smax += p[1]; svar += p[2];
    }
    float mean_sim = ssum / ((float)SQL * (float)SKL);
    float max_sim  = smax / (float)SQL;
    float entropy  = svar / (float)SQL;
    mean_sim = fminf(fmaxf(mean_sim, -10.f), 10.f);
    max_sim  = fminf(fmaxf(max_sim,  -10.f), 10.f);
    entropy  = fminf(fmaxf(entropy,    0.f), 1.f);
    float f0 = mean_sim, f1 = max_sim, f2 = entropy;
    float raw = b2[0];
    #pragma unroll
    for (int i = 0; i < 16; ++i) {
        float a = b1[i] + W1[i*3+0] * f0 + W1[i*3+1] * f1 + W1[i*3+2] * f2;
        raw += W2[i] * tanhf(a);
    }
    float t = 0.1f + 0.9f / (1.0f + __expf(-raw));
    t = fminf(fmaxf(t, 0.1f), 1.0f);
    out[h] = t;
}

extern "C" void kernel_launch(void* const* d_in, const int* in_sizes, int n_in,
                              void* d_out, int out_size, void* d_ws, size_t ws_size,
                              hipStream_t stream) {
    const float* Q  = (const float*)d_in[0];
    const float* K  = (const float*)d_in[1];
    const float* W1 = (const float*)d_in[2];
    const float* b1 = (const float*)d_in[3];
    const float* W2 = (const float*)d_in[4];
    const float* b2 = (const float*)d_in[5];
    float* out      = (float*)d_out;
    float* partial  = (float*)d_ws;   // 16*32*3 floats = 6 KB

    dim3 grid(SQL / QB, NH);  // (32, 16)
    dtp_stats_kernel<<<grid, 256, 0, stream>>>(Q, K, partial);
    dtp_finalize_kernel<<<1, 64, 0, stream>>>(partial, W1, b1, W2, b2, out);
}

// Round 2
// 94.332 us; speedup vs baseline: 4.8698x; 4.8698x over previous
//
#include <hip/hip_runtime.h>
#include <math.h>

#define NH   16
#define SQL  4096
#define SKL  4096
#define DK   64
#define QB   128
#define KB   128
#define NKT  (SKL / KB)

typedef __bf16 bf16x8 __attribute__((ext_vector_type(8)));
typedef __bf16 bf16x4 __attribute__((ext_vector_type(4)));
typedef float  f32x4  __attribute__((ext_vector_type(4)));

// XOR-swizzled byte address into a [rows][64] bf16 tile (row stride 128 B).
// 16-byte granule swizzle; write and read use the same mapping (T2, G4).
__device__ __forceinline__ int swz(int row, int col_bytes) {
    return ((row << 7) + col_bytes) ^ ((row & 7) << 4);
}

// Kernel 1: per-(head, q-block) streaming score statistics via bf16 MFMA.
__global__ __launch_bounds__(256, 2) void dtp_stats_mfma(const float* __restrict__ Q,
                                                         const float* __restrict__ K,
                                                         float* __restrict__ partial) {
    __shared__ __align__(16) unsigned char Qs[QB * DK * 2];  // 16 KB bf16, swizzled
    __shared__ __align__(16) unsigned char Ks[KB * DK * 2];  // 16 KB bf16, swizzled
    __shared__ float red[16][3];

    const int qb   = blockIdx.x;   // 0..31
    const int h    = blockIdx.y;   // 0..15
    const int tid  = threadIdx.x;
    const int lane = tid & 63;
    const int w    = tid >> 6;     // wave 0..3 -> rows w*32..w*32+31
    const int l15  = lane & 15;
    const int lg   = lane >> 4;    // 0..3

    const float* Qh = Q + ((size_t)h * SQL + (size_t)qb * QB) * DK;
    const float* Kh = K + (size_t)h * SKL * DK;

    // ---- stage Q once: fp32 -> bf16, swizzled ----
    #pragma unroll
    for (int j = 0; j < 8; ++j) {
        int idx = tid + 256 * j;      // 0..2047
        int r   = idx >> 4;           // 0..127
        int c4  = idx & 15;           // float4 chunk along d
        const float4 v = *reinterpret_cast<const float4*>(Qh + r * DK + c4 * 4);
        bf16x4 hv;
        hv[0] = (__bf16)v.x; hv[1] = (__bf16)v.y; hv[2] = (__bf16)v.z; hv[3] = (__bf16)v.w;
        *reinterpret_cast<bf16x4*>(&Qs[swz(r, c4 * 8)]) = hv;
    }

    // ---- prefetch K tile 0 into registers ----
    float4 kreg[8];
    #pragma unroll
    for (int j = 0; j < 8; ++j) {
        int idx = tid + 256 * j;
        int r   = idx >> 4;
        int c4  = idx & 15;
        kreg[j] = *reinterpret_cast<const float4*>(Kh + (size_t)r * DK + c4 * 4);
    }

    // per-lane running stats for its 8 rows (index = rt*4 + reg)
    float rsum[8], rmx[8], rs1[8], rs2[8];
    #pragma unroll
    for (int i = 0; i < 8; ++i) { rsum[i] = 0.f; rmx[i] = -3.0e38f; rs1[i] = 0.f; rs2[i] = 0.f; }

    for (int kt = 0; kt < NKT; ++kt) {
        __syncthreads();   // previous compute done (also: Q writes visible at kt=0)
        // ---- write prefetched K tile: fp32 -> bf16, swizzled ----
        #pragma unroll
        for (int j = 0; j < 8; ++j) {
            int idx = tid + 256 * j;
            int r   = idx >> 4;
            int c4  = idx & 15;
            bf16x4 hv;
            hv[0] = (__bf16)kreg[j].x; hv[1] = (__bf16)kreg[j].y;
            hv[2] = (__bf16)kreg[j].z; hv[3] = (__bf16)kreg[j].w;
            *reinterpret_cast<bf16x4*>(&Ks[swz(r, c4 * 8)]) = hv;
        }
        __syncthreads();

        // ---- issue next K-tile global loads early (hide HBM/L2 latency under compute) ----
        if (kt + 1 < NKT) {
            const float* Kt = Kh + (size_t)(kt + 1) * KB * DK;
            #pragma unroll
            for (int j = 0; j < 8; ++j) {
                int idx = tid + 256 * j;
                int r   = idx >> 4;
                int c4  = idx & 15;
                kreg[j] = *reinterpret_cast<const float4*>(Kt + (size_t)r * DK + c4 * 4);
            }
        }

        // ---- A fragments: rows w*32 + rt*16 + l15, k = kk*32 + lg*8 + 0..7 ----
        bf16x8 aF[2][2];
        #pragma unroll
        for (int rt = 0; rt < 2; ++rt)
            #pragma unroll
            for (int kk = 0; kk < 2; ++kk) {
                int r = w * 32 + rt * 16 + l15;
                aF[rt][kk] = *reinterpret_cast<const bf16x8*>(&Qs[swz(r, kk * 64 + lg * 16)]);
            }

        // ---- 32x128 score tile for this wave: 16 mfma tiles ----
        f32x4 acc[2][8];
        #pragma unroll
        for (int ct = 0; ct < 8; ++ct) {
            bf16x8 bF[2];
            #pragma unroll
            for (int kk = 0; kk < 2; ++kk) {
                int r = ct * 16 + l15;
                bF[kk] = *reinterpret_cast<const bf16x8*>(&Ks[swz(r, kk * 64 + lg * 16)]);
            }
            #pragma unroll
            for (int rt = 0; rt < 2; ++rt) {
                f32x4 a = {0.f, 0.f, 0.f, 0.f};
                a = __builtin_amdgcn_mfma_f32_16x16x32_bf16(aF[rt][0], bF[0], a, 0, 0, 0);
                a = __builtin_amdgcn_mfma_f32_16x16x32_bf16(aF[rt][1], bF[1], a, 0, 0, 0);
                acc[rt][ct] = a;
            }
        }

        // ---- fold 64 scores/lane into row stats ----
        // c = raw dot (= 8*s); clamp at +-400 == clamp s at +-50; e = exp(c/16) = exp(s/2)
        #pragma unroll
        for (int rt = 0; rt < 2; ++rt)
            #pragma unroll
            for (int ct = 0; ct < 8; ++ct)
                #pragma unroll
                for (int r = 0; r < 4; ++r) {
                    float c  = acc[rt][ct][r];
                    float cc = fminf(fmaxf(c, -400.f), 400.f);
                    int   i  = rt * 4 + r;
                    rsum[i] += cc;
                    rmx[i]   = fmaxf(rmx[i], cc);
                    float e  = __expf(cc * 0.0625f);
                    rs1[i]  += e;
                    rs2[i]   = fmaf(e, e, rs2[i]);
                }
    }

    // ---- reduce across the 16 column-lanes (bits 0..3 of lane) ----
    #pragma unroll
    for (int i = 0; i < 8; ++i) {
        #pragma unroll
        for (int m = 1; m < 16; m <<= 1) {
            rsum[i] += __shfl_xor(rsum[i], m, 64);
            rmx[i]   = fmaxf(rmx[i], __shfl_xor(rmx[i], m, 64));
            rs1[i]  += __shfl_xor(rs1[i], m, 64);
            rs2[i]  += __shfl_xor(rs2[i], m, 64);
        }
    }

    if (l15 == 0) {
        float bs = 0.f, bm = 0.f, bv = 0.f;
        #pragma unroll
        for (int i = 0; i < 8; ++i) {
            bs += rsum[i];
            bm += rmx[i] * 0.125f;                       // scale raw max -> score max
            float sumP2 = rs2[i] / (rs1[i] * rs1[i]);    // shift-free sum of p^2
            bv += (sumP2 - 1.0f / (float)SKL) * (1.0f / (float)(SKL - 1));
        }
        red[w * 4 + lg][0] = bs;
        red[w * 4 + lg][1] = bm;
        red[w * 4 + lg][2] = bv;
    }
    __syncthreads();
    if (tid == 0) {
        float bs = 0.f, bm = 0.f, bv = 0.f;
        #pragma unroll
        for (int i = 0; i < 16; ++i) { bs += red[i][0]; bm += red[i][1]; bv += red[i][2]; }
        float* p = partial + (size_t)(h * 32 + qb) * 3;
        p[0] = bs * 0.125f;   // raw-sum -> score-sum
        p[1] = bm;
        p[2] = bv;
    }
}

// Kernel 2: reduce block partials per head, apply 3->16->1 MLP, write t.
__global__ __launch_bounds__(64) void dtp_finalize_kernel(const float* __restrict__ partial,
                                                          const float* __restrict__ W1,
                                                          const float* __restrict__ b1,
                                                          const float* __restrict__ W2,
                                                          const float* __restrict__ b2,
                                                          float* __restrict__ out) {
    int h = threadIdx.x;
    if (h >= NH) return;
    float ssum = 0.f, smax = 0.f, svar = 0.f;
    for (int qb = 0; qb < 32; ++qb) {
        const float* p = partial + (size_t)(h * 32 + qb) * 3;
        ssum += p[0]; smax += p[1]; svar += p[2];
    }
    float mean_sim = ssum / ((float)SQL * (float)SKL);
    float max_sim  = smax / (float)SQL;
    float entropy  = svar / (float)SQL;
    mean_sim = fminf(fmaxf(mean_sim, -10.f), 10.f);
    max_sim  = fminf(fmaxf(max_sim,  -10.f), 10.f);
    entropy  = fminf(fmaxf(entropy,    0.f), 1.f);
    float raw = b2[0];
    #pragma unroll
    for (int i = 0; i < 16; ++i) {
        float a = b1[i] + W1[i*3+0] * mean_sim + W1[i*3+1] * max_sim + W1[i*3+2] * entropy;
        raw += W2[i] * tanhf(a);
    }
    float t = 0.1f + 0.9f / (1.0f + __expf(-raw));
    t = fminf(fmaxf(t, 0.1f), 1.0f);
    out[h] = t;
}

extern "C" void kernel_launch(void* const* d_in, const int* in_sizes, int n_in,
                              void* d_out, int out_size, void* d_ws, size_t ws_size,
                              hipStream_t stream) {
    const float* Q  = (const float*)d_in[0];
    const float* K  = (const float*)d_in[1];
    const float* W1 = (const float*)d_in[2];
    const float* b1 = (const float*)d_in[3];
    const float* W2 = (const float*)d_in[4];
    const float* b2 = (const float*)d_in[5];
    float* out      = (float*)d_out;
    float* partial  = (float*)d_ws;   // 16*32*3 floats = 6 KB

    dim3 grid(SQL / QB, NH);  // (32, 16), x-fastest => same-head blocks adjacent
    dtp_stats_mfma<<<grid, 256, 0, stream>>>(Q, K, partial);
    dtp_finalize_kernel<<<1, 64, 0, stream>>>(partial, W1, b1, W2, b2, out);
}

// Round 3
// 81.329 us; speedup vs baseline: 5.6484x; 1.1599x over previous
//
#include <hip/hip_runtime.h>
#include <math.h>

#define NH   16
#define SQL  4096
#define SKL  4096
#define DK   64
#define QB   128
#define KB   128
#define NKT  (SKL / KB)

// Q pre-scale: MFMA then yields dot' = s * 0.5*log2(e), so exp2(dot') = exp(s/2)
#define QSCALE  0.090168440f      // 0.125 * 0.5 * log2(e)
#define UNSCALE 1.3862943611f     // 2*ln2 : dot' -> s

typedef __bf16 bf16x8 __attribute__((ext_vector_type(8)));
typedef __bf16 bf16x4 __attribute__((ext_vector_type(4)));
typedef float  f32x4  __attribute__((ext_vector_type(4)));

#if __has_builtin(__builtin_amdgcn_exp2f)
#define EXP2(x) __builtin_amdgcn_exp2f(x)
#else
#define EXP2(x) exp2f(x)
#endif

// XOR-swizzled byte address into a [rows][64] bf16 tile (row stride 128 B).
__device__ __forceinline__ int swz(int row, int col_bytes) {
    return ((row << 7) + col_bytes) ^ ((row & 7) << 4);
}

// Kernel 1: per-(head, q-block) streaming score statistics via bf16 MFMA.
// 8 waves, 16 q-rows per wave.
__global__ __launch_bounds__(512, 4) void dtp_stats_mfma(const float* __restrict__ Q,
                                                         const float* __restrict__ K,
                                                         float* __restrict__ partial) {
    __shared__ __align__(16) unsigned char Qs[QB * DK * 2];  // 16 KB bf16, swizzled, pre-scaled
    __shared__ __align__(16) unsigned char Ks[KB * DK * 2];  // 16 KB bf16, swizzled
    __shared__ float red[32][3];

    const int qb   = blockIdx.x;   // 0..31
    const int h    = blockIdx.y;   // 0..15
    const int tid  = threadIdx.x;
    const int lane = tid & 63;
    const int w    = tid >> 6;     // wave 0..7 -> q-rows w*16..w*16+15
    const int l15  = lane & 15;
    const int lg   = lane >> 4;    // 0..3

    const float* Qh = Q + ((size_t)h * SQL + (size_t)qb * QB) * DK;
    const float* Kh = K + (size_t)h * SKL * DK;

    // ---- stage Q once: fp32 -> bf16 (pre-scaled), swizzled ----
    #pragma unroll
    for (int j = 0; j < 4; ++j) {
        int idx = tid + 512 * j;      // 0..2047
        int r   = idx >> 4;           // 0..127
        int c4  = idx & 15;           // float4 chunk along d (constant per thread)
        const float4 v = *reinterpret_cast<const float4*>(Qh + r * DK + c4 * 4);
        bf16x4 hv;
        hv[0] = (__bf16)(v.x * QSCALE); hv[1] = (__bf16)(v.y * QSCALE);
        hv[2] = (__bf16)(v.z * QSCALE); hv[3] = (__bf16)(v.w * QSCALE);
        *reinterpret_cast<bf16x4*>(&Qs[swz(r, c4 * 8)]) = hv;
    }

    // ---- prefetch K tile 0 into registers ----
    float4 kreg[4];
    #pragma unroll
    for (int j = 0; j < 4; ++j) {
        int idx = tid + 512 * j;
        int r   = idx >> 4;
        int c4  = idx & 15;
        kreg[j] = *reinterpret_cast<const float4*>(Kh + (size_t)r * DK + c4 * 4);
    }

    __syncthreads();   // Q staged

    // ---- hoisted A fragments (Q invariant across K-tiles) ----
    bf16x8 aF[2];
    {
        int r = w * 16 + l15;
        aF[0] = *reinterpret_cast<const bf16x8*>(&Qs[swz(r, 0 * 64 + lg * 16)]);
        aF[1] = *reinterpret_cast<const bf16x8*>(&Qs[swz(r, 1 * 64 + lg * 16)]);
    }

    // per-lane running stats for its 4 rows (row = lg*4 + reg within wave tile)
    float rsum[4], rmx[4], rs1[4], rs2[4];
    #pragma unroll
    for (int i = 0; i < 4; ++i) { rsum[i] = 0.f; rmx[i] = -3.0e38f; rs1[i] = 0.f; rs2[i] = 0.f; }

    for (int kt = 0; kt < NKT; ++kt) {
        __syncthreads();   // previous tile's compute done
        // ---- write prefetched K tile: fp32 -> bf16, swizzled ----
        #pragma unroll
        for (int j = 0; j < 4; ++j) {
            int idx = tid + 512 * j;
            int r   = idx >> 4;
            int c4  = idx & 15;
            bf16x4 hv;
            hv[0] = (__bf16)kreg[j].x; hv[1] = (__bf16)kreg[j].y;
            hv[2] = (__bf16)kreg[j].z; hv[3] = (__bf16)kreg[j].w;
            *reinterpret_cast<bf16x4*>(&Ks[swz(r, c4 * 8)]) = hv;
        }
        __syncthreads();

        // ---- issue next K-tile global loads early ----
        if (kt + 1 < NKT) {
            const float* Kt = Kh + (size_t)(kt + 1) * KB * DK;
            #pragma unroll
            for (int j = 0; j < 4; ++j) {
                int idx = tid + 512 * j;
                int r   = idx >> 4;
                int c4  = idx & 15;
                kreg[j] = *reinterpret_cast<const float4*>(Kt + (size_t)r * DK + c4 * 4);
            }
        }

        // ---- 16x128 score tile for this wave: 16 mfma ----
        f32x4 acc[8];
        #pragma unroll
        for (int ct = 0; ct < 8; ++ct) {
            int rr = ct * 16 + l15;
            bf16x8 b0 = *reinterpret_cast<const bf16x8*>(&Ks[swz(rr, 0 * 64 + lg * 16)]);
            bf16x8 b1 = *reinterpret_cast<const bf16x8*>(&Ks[swz(rr, 1 * 64 + lg * 16)]);
            f32x4 a = {0.f, 0.f, 0.f, 0.f};
            a = __builtin_amdgcn_mfma_f32_16x16x32_bf16(aF[0], b0, a, 0, 0, 0);
            a = __builtin_amdgcn_mfma_f32_16x16x32_bf16(aF[1], b1, a, 0, 0, 0);
            acc[ct] = a;
        }

        // ---- fold 32 scores/lane into row stats (scaled units, no clamp) ----
        #pragma unroll
        for (int r = 0; r < 4; ++r) {
            float v0 = acc[0][r], v1 = acc[1][r], v2 = acc[2][r], v3 = acc[3][r];
            float v4 = acc[4][r], v5 = acc[5][r], v6 = acc[6][r], v7 = acc[7][r];
            rsum[r] += ((v0 + v1) + (v2 + v3)) + ((v4 + v5) + (v6 + v7));
            rmx[r] = fmaxf(rmx[r],
                     fmaxf(fmaxf(fmaxf(v0, v1), fmaxf(v2, v3)),
                           fmaxf(fmaxf(v4, v5), fmaxf(v6, v7))));
            float e0 = EXP2(v0), e1 = EXP2(v1), e2 = EXP2(v2), e3 = EXP2(v3);
            float e4 = EXP2(v4), e5 = EXP2(v5), e6 = EXP2(v6), e7 = EXP2(v7);
            rs1[r] += ((e0 + e1) + (e2 + e3)) + ((e4 + e5) + (e6 + e7));
            float t0 = fmaf(e0, e0, e1 * e1), t1 = fmaf(e2, e2, e3 * e3);
            float t2 = fmaf(e4, e4, e5 * e5), t3 = fmaf(e6, e6, e7 * e7);
            rs2[r] += (t0 + t1) + (t2 + t3);
        }
    }

    // ---- reduce across the 16 column-lanes (bits 0..3 of lane id) ----
    #pragma unroll
    for (int i = 0; i < 4; ++i) {
        #pragma unroll
        for (int m = 1; m < 16; m <<= 1) {
            rsum[i] += __shfl_xor(rsum[i], m, 64);
            rmx[i]   = fmaxf(rmx[i], __shfl_xor(rmx[i], m, 64));
            rs1[i]  += __shfl_xor(rs1[i], m, 64);
            rs2[i]  += __shfl_xor(rs2[i], m, 64);
        }
    }

    if (l15 == 0) {
        float bs = 0.f, bm = 0.f, bv = 0.f;
        #pragma unroll
        for (int r = 0; r < 4; ++r) {
            bs += rsum[r];
            bm += rmx[r];
            float sumP2 = rs2[r] / (rs1[r] * rs1[r]);    // shift-free sum of p^2
            bv += (sumP2 - 1.0f / (float)SKL) * (1.0f / (float)(SKL - 1));
        }
        red[w * 4 + lg][0] = bs * UNSCALE;   // scaled-dot -> score units
        red[w * 4 + lg][1] = bm * UNSCALE;
        red[w * 4 + lg][2] = bv;
    }
    __syncthreads();
    if (tid == 0) {
        float bs = 0.f, bm = 0.f, bv = 0.f;
        #pragma unroll
        for (int i = 0; i < 32; ++i) { bs += red[i][0]; bm += red[i][1]; bv += red[i][2]; }
        float* p = partial + (size_t)(h * 32 + qb) * 3;
        p[0] = bs; p[1] = bm; p[2] = bv;
    }
}

// Kernel 2: reduce block partials per head, apply 3->16->1 MLP, write t.
__global__ __launch_bounds__(64) void dtp_finalize_kernel(const float* __restrict__ partial,
                                                          const float* __restrict__ W1,
                                                          const float* __restrict__ b1,
                                                          const float* __restrict__ W2,
                                                          const float* __restrict__ b2,
                                                          float* __restrict__ out) {
    int h = threadIdx.x;
    if (h >= NH) return;
    float ssum = 0.f, smax = 0.f, svar = 0.f;
    for (int qb = 0; qb < 32; ++qb) {
        const float* p = partial + (size_t)(h * 32 + qb) * 3;
        ssum += p[0]; smax += p[1]; svar += p[2];
    }
    float mean_sim = ssum / ((float)SQL * (float)SKL);
    float max_sim  = smax / (float)SQL;
    float entropy  = svar / (float)SQL;
    mean_sim = fminf(fmaxf(mean_sim, -10.f), 10.f);
    max_sim  = fminf(fmaxf(max_sim,  -10.f), 10.f);
    entropy  = fminf(fmaxf(entropy,    0.f), 1.f);
    float raw = b2[0];
    #pragma unroll
    for (int i = 0; i < 16; ++i) {
        float a = b1[i] + W1[i*3+0] * mean_sim + W1[i*3+1] * max_sim + W1[i*3+2] * entropy;
        raw += W2[i] * tanhf(a);
    }
    float t = 0.1f + 0.9f / (1.0f + __expf(-raw));
    t = fminf(fmaxf(t, 0.1f), 1.0f);
    out[h] = t;
}

extern "C" void kernel_launch(void* const* d_in, const int* in_sizes, int n_in,
                              void* d_out, int out_size, void* d_ws, size_t ws_size,
                              hipStream_t stream) {
    const float* Q  = (const float*)d_in[0];
    const float* K  = (const float*)d_in[1];
    const float* W1 = (const float*)d_in[2];
    const float* b1 = (const float*)d_in[3];
    const float* W2 = (const float*)d_in[4];
    const float* b2 = (const float*)d_in[5];
    float* out      = (float*)d_out;
    float* partial  = (float*)d_ws;   // 16*32*3 floats = 6 KB

    dim3 grid(SQL / QB, NH);  // (32, 16)
    dtp_stats_mfma<<<grid, 512, 0, stream>>>(Q, K, partial);
    dtp_finalize_kernel<<<1, 64, 0, stream>>>(partial, W1, b1, W2, b2, out);
}

// Round 4
// 75.696 us; speedup vs baseline: 6.0687x; 1.0744x over previous
//
#include <hip/hip_runtime.h>
#include <math.h>

#define NH   16
#define SQL  4096
#define SKL  4096
#define DK   64
#define QB   128
#define KB   128
#define NKT  (SKL / KB)

// Q pre-scale: MFMA then yields dot' = s * 0.5*log2(e), so exp2(dot') = exp(s/2)
#define QSCALE  0.090168440f      // 0.125 * 0.5 * log2(e)
#define UNSCALE 1.3862943611f     // 2*ln2 : dot' -> s

typedef __bf16 bf16x8 __attribute__((ext_vector_type(8)));
typedef __bf16 bf16x4 __attribute__((ext_vector_type(4)));
typedef float  f32x4  __attribute__((ext_vector_type(4)));
typedef float  f32x2  __attribute__((ext_vector_type(2)));

#if __has_builtin(__builtin_amdgcn_exp2f)
#define EXP2(x) __builtin_amdgcn_exp2f(x)
#else
#define EXP2(x) exp2f(x)
#endif

static __device__ __forceinline__ f32x2 pk_fma(f32x2 a, f32x2 b, f32x2 c) {
#if __has_builtin(__builtin_elementwise_fma)
    return __builtin_elementwise_fma(a, b, c);
#else
    f32x2 r; r[0] = fmaf(a[0], b[0], c[0]); r[1] = fmaf(a[1], b[1], c[1]); return r;
#endif
}
static __device__ __forceinline__ f32x2 pk_max(f32x2 a, f32x2 b) {
#if __has_builtin(__builtin_elementwise_max)
    return __builtin_elementwise_max(a, b);
#else
    f32x2 r; r[0] = fmaxf(a[0], b[0]); r[1] = fmaxf(a[1], b[1]); return r;
#endif
}

// XOR-swizzled byte address into a [rows][64] bf16 tile (row stride 128 B).
__device__ __forceinline__ int swz(int row, int col_bytes) {
    return ((row << 7) + col_bytes) ^ ((row & 7) << 4);
}

// Kernel 1: per-(head, q-block) streaming score statistics via bf16 MFMA.
// 8 waves, 16 q-rows per wave; double-buffered K tiles, 1 barrier/tile.
__global__ __launch_bounds__(512, 4) void dtp_stats_mfma(const float* __restrict__ Q,
                                                         const float* __restrict__ K,
                                                         float* __restrict__ partial) {
    __shared__ __align__(16) unsigned char Qs[QB * DK * 2];        // 16 KB, pre-scaled bf16
    __shared__ __align__(16) unsigned char Ks[2][KB * DK * 2];     // 2 x 16 KB, bf16
    __shared__ float red[32][3];

    const int qb   = blockIdx.x;   // 0..31
    const int h    = blockIdx.y;   // 0..15
    const int tid  = threadIdx.x;
    const int lane = tid & 63;
    const int w    = tid >> 6;     // wave 0..7 -> q-rows w*16..w*16+15
    const int l15  = lane & 15;
    const int lg   = lane >> 4;    // 0..3

    const float* Qh = Q + ((size_t)h * SQL + (size_t)qb * QB) * DK;
    const float* Kh = K + (size_t)h * SKL * DK;

    // per-thread staging coords: c4 fixed, rows r0+32j
    const int sc4 = tid & 15;
    const int sr0 = tid >> 4;

    // ---- stage Q once: fp32 -> bf16 (pre-scaled), swizzled ----
    #pragma unroll
    for (int j = 0; j < 4; ++j) {
        int r = sr0 + 32 * j;
        const float4 v = *reinterpret_cast<const float4*>(Qh + r * DK + sc4 * 4);
        bf16x4 hv;
        hv[0] = (__bf16)(v.x * QSCALE); hv[1] = (__bf16)(v.y * QSCALE);
        hv[2] = (__bf16)(v.z * QSCALE); hv[3] = (__bf16)(v.w * QSCALE);
        *reinterpret_cast<bf16x4*>(&Qs[swz(r, sc4 * 8)]) = hv;
    }

    // ---- prologue: tile 0 -> regs -> Ks[0]; prefetch tile 1 -> regs ----
    float4 kreg[4];
    #pragma unroll
    for (int j = 0; j < 4; ++j)
        kreg[j] = *reinterpret_cast<const float4*>(Kh + (size_t)(sr0 + 32 * j) * DK + sc4 * 4);
    #pragma unroll
    for (int j = 0; j < 4; ++j) {
        int r = sr0 + 32 * j;
        bf16x4 hv;
        hv[0] = (__bf16)kreg[j].x; hv[1] = (__bf16)kreg[j].y;
        hv[2] = (__bf16)kreg[j].z; hv[3] = (__bf16)kreg[j].w;
        *reinterpret_cast<bf16x4*>(&Ks[0][swz(r, sc4 * 8)]) = hv;
    }
    #pragma unroll
    for (int j = 0; j < 4; ++j)
        kreg[j] = *reinterpret_cast<const float4*>(Kh + (size_t)(KB + sr0 + 32 * j) * DK + sc4 * 4);

    __syncthreads();   // Qs + Ks[0] visible

    // ---- hoisted A fragments (Q invariant across K-tiles) ----
    bf16x8 aF[2];
    {
        int r = w * 16 + l15;
        aF[0] = *reinterpret_cast<const bf16x8*>(&Qs[swz(r, 0 * 64 + lg * 16)]);
        aF[1] = *reinterpret_cast<const bf16x8*>(&Qs[swz(r, 1 * 64 + lg * 16)]);
    }

    // packed per-lane stats: component 0 <-> acc reg {0,2}, rows paired (0,1) and (2,3)
    f32x2 rsum01 = {0.f, 0.f}, rsum23 = {0.f, 0.f};
    f32x2 rmx01  = {-3.0e38f, -3.0e38f}, rmx23 = {-3.0e38f, -3.0e38f};
    f32x2 rs1_01 = {0.f, 0.f}, rs1_23 = {0.f, 0.f};
    f32x2 rs2_01 = {0.f, 0.f}, rs2_23 = {0.f, 0.f};

    for (int kt = 0; kt < NKT; ++kt) {
        const int cur = kt & 1;

        // ---- stage tile kt+1 into alternate buffer (no barrier needed: disjoint) ----
        if (kt + 1 < NKT) {
            #pragma unroll
            for (int j = 0; j < 4; ++j) {
                int r = sr0 + 32 * j;
                bf16x4 hv;
                hv[0] = (__bf16)kreg[j].x; hv[1] = (__bf16)kreg[j].y;
                hv[2] = (__bf16)kreg[j].z; hv[3] = (__bf16)kreg[j].w;
                *reinterpret_cast<bf16x4*>(&Ks[cur ^ 1][swz(r, sc4 * 8)]) = hv;
            }
            if (kt + 2 < NKT) {
                const float* Kt = Kh + (size_t)(kt + 2) * KB * DK;
                #pragma unroll
                for (int j = 0; j < 4; ++j)
                    kreg[j] = *reinterpret_cast<const float4*>(Kt + (size_t)(sr0 + 32 * j) * DK + sc4 * 4);
            }
        }

        // ---- 16x128 score tile for this wave: 16 mfma ----
        f32x4 acc[8];
        #pragma unroll
        for (int ct = 0; ct < 8; ++ct) {
            int rr = ct * 16 + l15;
            bf16x8 b0 = *reinterpret_cast<const bf16x8*>(&Ks[cur][swz(rr, 0 * 64 + lg * 16)]);
            bf16x8 b1 = *reinterpret_cast<const bf16x8*>(&Ks[cur][swz(rr, 1 * 64 + lg * 16)]);
            f32x4 a = {0.f, 0.f, 0.f, 0.f};
            a = __builtin_amdgcn_mfma_f32_16x16x32_bf16(aF[0], b0, a, 0, 0, 0);
            a = __builtin_amdgcn_mfma_f32_16x16x32_bf16(aF[1], b1, a, 0, 0, 0);
            acc[ct] = a;
        }

        // ---- packed fold: rows paired (0,1)/(2,3) are consecutive acc VGPRs ----
        f32x2 s01 = {0.f, 0.f}, s23 = {0.f, 0.f};
        #pragma unroll
        for (int ct = 0; ct < 8; ++ct) {
            f32x2 v01 = __builtin_shufflevector(acc[ct], acc[ct], 0, 1);
            f32x2 v23 = __builtin_shufflevector(acc[ct], acc[ct], 2, 3);
            s01 += v01; s23 += v23;
            rmx01 = pk_max(rmx01, v01);
            rmx23 = pk_max(rmx23, v23);
            f32x2 e01, e23;
            e01[0] = EXP2(v01[0]); e01[1] = EXP2(v01[1]);
            e23[0] = EXP2(v23[0]); e23[1] = EXP2(v23[1]);
            rs1_01 += e01; rs1_23 += e23;
            rs2_01 = pk_fma(e01, e01, rs2_01);
            rs2_23 = pk_fma(e23, e23, rs2_23);
        }
        rsum01 += s01; rsum23 += s23;

        __syncthreads();   // Ks[cur^1] writes visible; Ks[cur] reads done
    }

    // ---- reduce across the 16 column-lanes (bits 0..3 of lane id) ----
    #pragma unroll
    for (int m = 1; m < 16; m <<= 1) {
        #pragma unroll
        for (int c = 0; c < 2; ++c) {
            rsum01[c] += __shfl_xor(rsum01[c], m, 64);
            rsum23[c] += __shfl_xor(rsum23[c], m, 64);
            rmx01[c]   = fmaxf(rmx01[c], __shfl_xor(rmx01[c], m, 64));
            rmx23[c]   = fmaxf(rmx23[c], __shfl_xor(rmx23[c], m, 64));
            rs1_01[c] += __shfl_xor(rs1_01[c], m, 64);
            rs1_23[c] += __shfl_xor(rs1_23[c], m, 64);
            rs2_01[c] += __shfl_xor(rs2_01[c], m, 64);
            rs2_23[c] += __shfl_xor(rs2_23[c], m, 64);
        }
    }

    if (l15 == 0) {
        float bs = (rsum01[0] + rsum01[1]) + (rsum23[0] + rsum23[1]);
        float bm = (rmx01[0] + rmx01[1]) + (rmx23[0] + rmx23[1]);
        float bv = 0.f;
        const float invSK = 1.0f / (float)SKL, invSK1 = 1.0f / (float)(SKL - 1);
        {
            float r1[4] = {rs1_01[0], rs1_01[1], rs1_23[0], rs1_23[1]};
            float r2[4] = {rs2_01[0], rs2_01[1], rs2_23[0], rs2_23[1]};
            #pragma unroll
            for (int i = 0; i < 4; ++i)
                bv += (r2[i] / (r1[i] * r1[i]) - invSK) * invSK1;
        }
        red[w * 4 + lg][0] = bs * UNSCALE;
        red[w * 4 + lg][1] = bm * UNSCALE;
        red[w * 4 + lg][2] = bv;
    }
    __syncthreads();
    if (tid == 0) {
        float bs = 0.f, bm = 0.f, bv = 0.f;
        #pragma unroll
        for (int i = 0; i < 32; ++i) { bs += red[i][0]; bm += red[i][1]; bv += red[i][2]; }
        float* p = partial + (size_t)(h * 32 + qb) * 3;
        p[0] = bs; p[1] = bm; p[2] = bv;
    }
}

// Kernel 2: reduce block partials per head, apply 3->16->1 MLP, write t.
__global__ __launch_bounds__(64) void dtp_finalize_kernel(const float* __restrict__ partial,
                                                          const float* __restrict__ W1,
                                                          const float* __restrict__ b1,
                                                          const float* __restrict__ W2,
                                                          const float* __restrict__ b2,
                                                          float* __restrict__ out) {
    int h = threadIdx.x;
    if (h >= NH) return;
    float ssum = 0.f, smax = 0.f, svar = 0.f;
    for (int qb = 0; qb < 32; ++qb) {
        const float* p = partial + (size_t)(h * 32 + qb) * 3;
        ssum += p[0]; smax += p[1]; svar += p[2];
    }
    float mean_sim = ssum / ((float)SQL * (float)SKL);
    float max_sim  = smax / (float)SQL;
    float entropy  = svar / (float)SQL;
    mean_sim = fminf(fmaxf(mean_sim, -10.f), 10.f);
    max_sim  = fminf(fmaxf(max_sim,  -10.f), 10.f);
    entropy  = fminf(fmaxf(entropy,    0.f), 1.f);
    float raw = b2[0];
    #pragma unroll
    for (int i = 0; i < 16; ++i) {
        float a = b1[i] + W1[i*3+0] * mean_sim + W1[i*3+1] * max_sim + W1[i*3+2] * entropy;
        raw += W2[i] * tanhf(a);
    }
    float t = 0.1f + 0.9f / (1.0f + __expf(-raw));
    t = fminf(fmaxf(t, 0.1f), 1.0f);
    out[h] = t;
}

extern "C" void kernel_launch(void* const* d_in, const int* in_sizes, int n_in,
                              void* d_out, int out_size, void* d_ws, size_t ws_size,
                              hipStream_t stream) {
    const float* Q  = (const float*)d_in[0];
    const float* K  = (const float*)d_in[1];
    const float* W1 = (const float*)d_in[2];
    const float* b1 = (const float*)d_in[3];
    const float* W2 = (const float*)d_in[4];
    const float* b2 = (const float*)d_in[5];
    float* out      = (float*)d_out;
    float* partial  = (float*)d_ws;   // 16*32*3 floats = 6 KB

    dim3 grid(SQL / QB, NH);  // (32, 16)
    dtp_stats_mfma<<<grid, 512, 0, stream>>>(Q, K, partial);
    dtp_finalize_kernel<<<1, 64, 0, stream>>>(partial, W1, b1, W2, b2, out);
}